// Round 4
// baseline (215.665 us; speedup 1.0000x reference)
//
#include <hip/hip_runtime.h>

// Q: (2, 5120, 5120) fp32, block-tridiagonal in 1024-blocks; >99% zeros.
// Pipeline (2 launches):
//   tables_fused : decode params -> A-stencil (LDS, per block) and emit
//                    offd[i][p][9]  = -0.5*(invM+invM^T) entries
//                    diag[j][p][25] = B0^T B0+I+.05 (rb=0) or
//                                     0.5*(M2+M2^T)+I?+.05 (rb>=1), j=b*5+rb
//                  grid (10 j, 16 p-slices) x 256; Ac recomputed per block in
//                  LDS (36 KB) -- decode is ~50 flops/entry, recompute is free
//                  vs. a third dispatch (~8 us/dispatch observed R0 vs R3).
//   fill2        : fused zero+band streaming fill, 64 B/thread.
//                  One block per (row,b); thread t owns float4-slot t of ALL
//                  FIVE column-blocks (same qx-window, dy uniform) -> band
//                  lookup computed once, selected per cb. Regular stores
//                  (NT stores just shift eviction cost to the harness's
//                  re-poison fill -- measured R2).

#define OFFD_OFF 73728           // floats; offd = 8*1024*9
#define DIAG_OFF 147456          // diag = 10*1024*25
// ws floats used: 147456 + 256000 = 403456 (~1.6 MB)

typedef float vfloat4 __attribute__((ext_vector_type(4)));

__device__ __forceinline__ float softplus10(float x) {
  float z = 10.f * x;
  return (fmaxf(z, 0.f) + log1pf(expf(-fabsf(z)))) * 0.1f;
}

// M2 entry from LDS stencil table: (A+I)^2 at (p,q), A implicit via ac[].
__device__ __forceinline__ float m2e_lds(const float* ac, int p, int q) {
  int px = p & 31, py = p >> 5, qx = q & 31, qy = q >> 5;
  float s = 0.f;
  #pragma unroll
  for (int o = 0; o < 9; o++) {
    const int dx = o % 3 - 1, dy = o / 3 - 1;
    int kx = px + dx, ky = py + dy;
    if (kx < 0 || kx > 31 || ky < 0 || ky > 31) continue;
    int k = ky * 32 + kx;
    float a = ac[p * 9 + o] + (o == 4 ? 1.f : 0.f);
    int ddx = qx - kx, ddy = qy - ky;
    if (ddx < -1 || ddx > 1 || ddy < -1 || ddy > 1) continue;
    float bb = ac[k * 9 + (ddy + 1) * 3 + (ddx + 1)] + (k == q ? 1.f : 0.f);
    s += a * bb;
  }
  return s;
}

// B0^T B0 entry from LDS stencil table.
__device__ __forceinline__ float btb_lds(const float* ac, int p, int q) {
  int px = p & 31, py = p >> 5, qx = q & 31, qy = q >> 5;
  float s = 0.f;
  #pragma unroll
  for (int o = 0; o < 9; o++) {
    const int dx = o % 3 - 1, dy = o / 3 - 1;
    int kx = px + dx, ky = py + dy;
    if (kx < 0 || kx > 31 || ky < 0 || ky > 31) continue;
    int k = ky * 32 + kx;
    float bkp = ac[k * 9 + (8 - o)];
    int ddx = qx - kx, ddy = qy - ky;
    if (ddx < -1 || ddx > 1 || ddy < -1 || ddy > 1) continue;
    float bkq = ac[k * 9 + (ddy + 1) * 3 + (ddx + 1)];
    s += bkp * bkq;
  }
  return s;
}

// grid (10, 16) x 256: block = (j = b*5+rb, p-slice sl of 64 rows).
__global__ __launch_bounds__(256) void tables_fused(
    const float* __restrict__ P0, float* __restrict__ ws) {
  __shared__ float ac[9216];     // 1024 x 9 stencil coeffs of A[i_ac]
  const int j  = blockIdx.x;     // 0..9
  const int sl = blockIdx.y;     // 0..15
  const int b  = j / 5, rb = j - b * 5;
  const int i_ac = b * 4 + (rb == 0 ? 0 : rb - 1);
  const int tt = (i_ac & 3) + 1; // time index 1..4
  const float* P = P0 + b * 35 * 1024;
  const int t = threadIdx.x;

  // ---- decode A[i_ac] into LDS (4 grid points per thread) ----
  #pragma unroll
  for (int k = 0; k < 4; k++) {
    int p = t + k * 256;
    // kappa/m: reference's raw-reshape axis mixing (q = p*5 + t)
    int qq = p * 5 + tt;
    int c  = qq >> 10;
    int r  = qq & 1023;
    float kap = softplus10(P[(0 + c) * 1024 + r]);
    float m1  = P[(5 + c) * 1024 + r];
    float m2  = P[(10 + c) * 1024 + r];
    // gamma/vx/vy: proper transpose layout
    float g  = softplus10(P[(15 + tt) * 1024 + p]);
    float vx = P[(20 + tt) * 1024 + p];
    float vy = P[(25 + tt) * 1024 + p];
    float H11 = g + vx * vx;
    float H22 = g + vy * vy;
    float H12 = vx * vy;
    float co[9];
    co[4] = kap * kap + 2.f * H11 + 2.f * H22;
    co[5] = -H11 + 0.5f * m1;
    co[3] = -H11 - 0.5f * m1;
    co[7] = -H22 + 0.5f * m2;
    co[1] = -H22 - 0.5f * m2;
    co[8] = -0.5f * H12;
    co[0] = -0.5f * H12;
    co[2] =  0.5f * H12;
    co[6] =  0.5f * H12;
    int px = p & 31, py = p >> 5;
    #pragma unroll
    for (int o = 0; o < 9; o++) {
      const int dx = o % 3 - 1, dy = o / 3 - 1;
      int nx = px + dx, ny = py + dy;
      bool valid = (nx >= 0) & (nx < 32) & (ny >= 0) & (ny < 32);
      ac[p * 9 + o] = (o == 4) ? co[4] : (valid ? co[o] : 0.f);
    }
  }
  __syncthreads();

  // ---- offd[i_ac] for this p-slice (rb>=1 blocks own i = b*4+rb-1) ----
  if (rb >= 1) {
    for (int e = t; e < 576; e += 256) {
      int pl = e / 9;
      int o  = e - pl * 9;
      int p  = sl * 64 + pl;
      int px = p & 31, py = p >> 5;
      float v = 0.f;
      if (o == 4) {
        v = -(ac[p * 9 + 4] + 1.f);
      } else {
        int dx = o % 3 - 1, dy = o / 3 - 1;
        int nx = px + dx, ny = py + dy;
        if (nx >= 0 && nx < 32 && ny >= 0 && ny < 32) {
          int q = ny * 32 + nx;
          v = -0.5f * (ac[p * 9 + o] + ac[q * 9 + (8 - o)]);
        }
      }
      ws[OFFD_OFF + (i_ac * 1024 + p) * 9 + o] = v;
    }
  }

  // ---- diag[j] for this p-slice ----
  for (int e = t; e < 1600; e += 256) {
    int pl = e / 25;
    int w  = e - pl * 25;
    int p  = sl * 64 + pl;
    int px = p & 31, py = p >> 5;
    int dx = w % 5 - 2, dy = w / 5 - 2;
    int nx = px + dx, ny = py + dy;
    float v = 0.f;
    if (nx >= 0 && nx < 32 && ny >= 0 && ny < 32) {
      int q = ny * 32 + nx;
      if (rb == 0) {
        v = btb_lds(ac, p, q) + (p == q ? 1.05f : 0.f);
      } else {
        float diagAdd = (rb <= 3 ? 1.05f : 0.05f);
        v = 0.5f * (m2e_lds(ac, p, q) + m2e_lds(ac, q, p)) + (p == q ? diagAdd : 0.f);
      }
    }
    ws[DIAG_OFF + (j * 1024 + p) * 25 + w] = v;
  }
}

// grid (5120, 2) x 256: block = (row, b); thread t owns float4-slot t in all
// five 1024-column blocks of the row. 5 x 16B stores = 80 B/thread.
__global__ __launch_bounds__(256) void fill2(
    const float* __restrict__ ws, float* __restrict__ out) {
  const int row = blockIdx.x;           // 0..5119
  const int b   = blockIdx.y;           // 0..1
  const int t   = threadIdx.x;          // 0..255
  const int rb  = row >> 10;
  const int p   = row & 1023;
  const int px  = p & 31, py = p >> 5;
  const int q0  = t * 4;
  const int qy  = q0 >> 5;
  const int qx0 = q0 & 31;
  const int dy  = qy - py;

  float dv[4] = {0.f, 0.f, 0.f, 0.f};
  float lv[4] = {0.f, 0.f, 0.f, 0.f};
  float rv[4] = {0.f, 0.f, 0.f, 0.f};

  // diag window (cb == rb)
  if (dy >= -2 && dy <= 2) {
    const float* tp = ws + DIAG_OFF +
        (((b * 5 + rb) * 1024 + p) * 25 + (dy + 2) * 5 + 2) - px;
    #pragma unroll
    for (int jj = 0; jj < 4; jj++) {
      int dx = qx0 + jj - px;
      if (dx >= -2 && dx <= 2) dv[jj] = tp[qx0 + jj];
    }
  }
  // offd windows (cb == rb-1 uses i=b*4+rb-1; cb == rb+1 uses i=b*4+rb)
  if (dy >= -1 && dy <= 1) {
    if (rb >= 1) {
      const float* tp = ws + OFFD_OFF +
          (((b * 4 + rb - 1) * 1024 + p) * 9 + (dy + 1) * 3 + 1) - px;
      #pragma unroll
      for (int jj = 0; jj < 4; jj++) {
        int dx = qx0 + jj - px;
        if (dx >= -1 && dx <= 1) lv[jj] = tp[qx0 + jj];
      }
    }
    if (rb <= 3) {
      const float* tp = ws + OFFD_OFF +
          (((b * 4 + rb) * 1024 + p) * 9 + (dy + 1) * 3 + 1) - px;
      #pragma unroll
      for (int jj = 0; jj < 4; jj++) {
        int dx = qx0 + jj - px;
        if (dx >= -1 && dx <= 1) rv[jj] = tp[qx0 + jj];
      }
    }
  }

  vfloat4* o4 = (vfloat4*)out;
  const long base = (long)b * 6553600 + (long)row * 1280 + t;
  #pragma unroll
  for (int cb = 0; cb < 5; cb++) {
    vfloat4 v = (vfloat4)(0.f);
    if (cb == rb) {
      v[0] = dv[0]; v[1] = dv[1]; v[2] = dv[2]; v[3] = dv[3];
    } else if (cb == rb - 1) {
      v[0] = lv[0]; v[1] = lv[1]; v[2] = lv[2]; v[3] = lv[3];
    } else if (cb == rb + 1) {
      v[0] = rv[0]; v[1] = rv[1]; v[2] = rv[2]; v[3] = rv[3];
    }
    o4[base + cb * 256] = v;
  }
}

extern "C" void kernel_launch(void* const* d_in, const int* in_sizes, int n_in,
                              void* d_out, int out_size, void* d_ws, size_t ws_size,
                              hipStream_t stream) {
  const float* params = (const float*)d_in[0];  // (2, 35, 32, 32) fp32
  float* ws = (float*)d_ws;                     // ~1.6 MB used
  float* out = (float*)d_out;                   // (2, 5120, 5120) fp32

  dim3 g1(10, 16);
  tables_fused<<<g1, 256, 0, stream>>>(params, ws);
  dim3 g2(5120, 2);
  fill2<<<g2, 256, 0, stream>>>(ws, out);
}

// Round 6
// 213.674 us; speedup vs baseline: 1.0093x; 1.0093x over previous
//
#include <hip/hip_runtime.h>

// Q: (2, 5120, 5120) fp32, block-tridiagonal in 1024-blocks; >99% zeros.
// Pipeline (2 launches):
//   tables_fused : decode params -> A-stencil (LDS, per block) and emit
//                    offd[i][p][9]  = -0.5*(invM+invM^T) entries
//                    diag[j][p][25] = B0^T B0+I+.05 (rb=0) or
//                                     0.5*(M2+M2^T)+I?+.05 (rb>=1), j=b*5+rb
//   fill_kernel  : single-pass streaming fill of all 210 MB, one float4 per
//                  thread with O(1) table lookup (R0 structure -- best
//                  measured portion ~79 us). Regular stores: NT stores just
//                  shift eviction cost to the harness poison fill (R2).
// NOTE: hipMemsetAsync inside kernel_launch crashed the container (R5) --
// do not reintroduce it.

#define OFFD_OFF 73728           // floats; offd = 8*1024*9
#define DIAG_OFF 147456          // diag = 10*1024*25
// ws floats used: 147456 + 256000 = 403456 (~1.6 MB)

typedef float vfloat4 __attribute__((ext_vector_type(4)));

__device__ __forceinline__ float softplus10(float x) {
  float z = 10.f * x;
  return (fmaxf(z, 0.f) + log1pf(expf(-fabsf(z)))) * 0.1f;
}

// M2 entry from LDS stencil table: (A+I)^2 at (p,q), A implicit via ac[].
__device__ __forceinline__ float m2e_lds(const float* ac, int p, int q) {
  int px = p & 31, py = p >> 5, qx = q & 31, qy = q >> 5;
  float s = 0.f;
  #pragma unroll
  for (int o = 0; o < 9; o++) {
    const int dx = o % 3 - 1, dy = o / 3 - 1;
    int kx = px + dx, ky = py + dy;
    if (kx < 0 || kx > 31 || ky < 0 || ky > 31) continue;
    int k = ky * 32 + kx;
    float a = ac[p * 9 + o] + (o == 4 ? 1.f : 0.f);
    int ddx = qx - kx, ddy = qy - ky;
    if (ddx < -1 || ddx > 1 || ddy < -1 || ddy > 1) continue;
    float bb = ac[k * 9 + (ddy + 1) * 3 + (ddx + 1)] + (k == q ? 1.f : 0.f);
    s += a * bb;
  }
  return s;
}

// B0^T B0 entry from LDS stencil table.
__device__ __forceinline__ float btb_lds(const float* ac, int p, int q) {
  int px = p & 31, py = p >> 5, qx = q & 31, qy = q >> 5;
  float s = 0.f;
  #pragma unroll
  for (int o = 0; o < 9; o++) {
    const int dx = o % 3 - 1, dy = o / 3 - 1;
    int kx = px + dx, ky = py + dy;
    if (kx < 0 || kx > 31 || ky < 0 || ky > 31) continue;
    int k = ky * 32 + kx;
    float bkp = ac[k * 9 + (8 - o)];
    int ddx = qx - kx, ddy = qy - ky;
    if (ddx < -1 || ddx > 1 || ddy < -1 || ddy > 1) continue;
    float bkq = ac[k * 9 + (ddy + 1) * 3 + (ddx + 1)];
    s += bkp * bkq;
  }
  return s;
}

// grid (10, 16) x 256: block = (j = b*5+rb, p-slice sl of 64 rows).
__global__ __launch_bounds__(256) void tables_fused(
    const float* __restrict__ P0, float* __restrict__ ws) {
  __shared__ float ac[9216];     // 1024 x 9 stencil coeffs of A[i_ac]
  const int j  = blockIdx.x;     // 0..9
  const int sl = blockIdx.y;     // 0..15
  const int b  = j / 5, rb = j - b * 5;
  const int i_ac = b * 4 + (rb == 0 ? 0 : rb - 1);
  const int tt = (i_ac & 3) + 1; // time index 1..4
  const float* P = P0 + b * 35 * 1024;
  const int t = threadIdx.x;

  // ---- decode A[i_ac] into LDS (4 grid points per thread) ----
  #pragma unroll
  for (int k = 0; k < 4; k++) {
    int p = t + k * 256;
    // kappa/m: reference's raw-reshape axis mixing (q = p*5 + t)
    int qq = p * 5 + tt;
    int c  = qq >> 10;
    int r  = qq & 1023;
    float kap = softplus10(P[(0 + c) * 1024 + r]);
    float m1  = P[(5 + c) * 1024 + r];
    float m2  = P[(10 + c) * 1024 + r];
    // gamma/vx/vy: proper transpose layout
    float g  = softplus10(P[(15 + tt) * 1024 + p]);
    float vx = P[(20 + tt) * 1024 + p];
    float vy = P[(25 + tt) * 1024 + p];
    float H11 = g + vx * vx;
    float H22 = g + vy * vy;
    float H12 = vx * vy;
    float co[9];
    co[4] = kap * kap + 2.f * H11 + 2.f * H22;
    co[5] = -H11 + 0.5f * m1;
    co[3] = -H11 - 0.5f * m1;
    co[7] = -H22 + 0.5f * m2;
    co[1] = -H22 - 0.5f * m2;
    co[8] = -0.5f * H12;
    co[0] = -0.5f * H12;
    co[2] =  0.5f * H12;
    co[6] =  0.5f * H12;
    int px = p & 31, py = p >> 5;
    #pragma unroll
    for (int o = 0; o < 9; o++) {
      const int dx = o % 3 - 1, dy = o / 3 - 1;
      int nx = px + dx, ny = py + dy;
      bool valid = (nx >= 0) & (nx < 32) & (ny >= 0) & (ny < 32);
      ac[p * 9 + o] = (o == 4) ? co[4] : (valid ? co[o] : 0.f);
    }
  }
  __syncthreads();

  // ---- offd[i_ac] for this p-slice (rb>=1 blocks own i = b*4+rb-1) ----
  if (rb >= 1) {
    for (int e = t; e < 576; e += 256) {
      int pl = e / 9;
      int o  = e - pl * 9;
      int p  = sl * 64 + pl;
      int px = p & 31, py = p >> 5;
      float v = 0.f;
      if (o == 4) {
        v = -(ac[p * 9 + 4] + 1.f);
      } else {
        int dx = o % 3 - 1, dy = o / 3 - 1;
        int nx = px + dx, ny = py + dy;
        if (nx >= 0 && nx < 32 && ny >= 0 && ny < 32) {
          int q = ny * 32 + nx;
          v = -0.5f * (ac[p * 9 + o] + ac[q * 9 + (8 - o)]);
        }
      }
      ws[OFFD_OFF + (i_ac * 1024 + p) * 9 + o] = v;
    }
  }

  // ---- diag[j] for this p-slice ----
  for (int e = t; e < 1600; e += 256) {
    int pl = e / 25;
    int w  = e - pl * 25;
    int p  = sl * 64 + pl;
    int px = p & 31, py = p >> 5;
    int dx = w % 5 - 2, dy = w / 5 - 2;
    int nx = px + dx, ny = py + dy;
    float v = 0.f;
    if (nx >= 0 && nx < 32 && ny >= 0 && ny < 32) {
      int q = ny * 32 + nx;
      if (rb == 0) {
        v = btb_lds(ac, p, q) + (p == q ? 1.05f : 0.f);
      } else {
        float diagAdd = (rb <= 3 ? 1.05f : 0.05f);
        v = 0.5f * (m2e_lds(ac, p, q) + m2e_lds(ac, q, p)) + (p == q ? diagAdd : 0.f);
      }
    }
    ws[DIAG_OFF + (j * 1024 + p) * 25 + w] = v;
  }
}

// grid (5, 5120, 2) x 256; one float4 per thread -- pure streaming write with
// O(1) table lookup (R0 structure, best measured).
__global__ __launch_bounds__(256) void fill_kernel(
    const float* __restrict__ ws, float* __restrict__ out) {
  const int cb  = blockIdx.x;
  const int row = blockIdx.y;
  const int b   = blockIdx.z;
  const int tx  = threadIdx.x;
  const int rb  = row >> 10;
  const int p   = row & 1023;
  const int d   = cb - rb;
  const long oidx = (long)b * 6553600 + (long)row * 1280 + cb * 256 + tx;

  float rr[4] = {0.f, 0.f, 0.f, 0.f};
  if (d >= -1 && d <= 1) {
    const int q0  = tx * 4;
    const int qy  = q0 >> 5;
    const int qx0 = q0 & 31;
    const int px  = p & 31, py = p >> 5;
    const int dy  = qy - py;
    if (d != 0) {
      if (dy >= -1 && dy <= 1) {
        const int i = b * 4 + (d > 0 ? rb : cb);
        const float* t = ws + OFFD_OFF + ((i * 1024 + p) * 9 + (dy + 1) * 3 + 1) - px;
        #pragma unroll
        for (int jj = 0; jj < 4; jj++) {
          int dx = qx0 + jj - px;
          if (dx >= -1 && dx <= 1) rr[jj] = t[qx0 + jj];
        }
      }
    } else {
      if (dy >= -2 && dy <= 2) {
        const int j = b * 5 + rb;
        const float* t = ws + DIAG_OFF + ((j * 1024 + p) * 25 + (dy + 2) * 5 + 2) - px;
        #pragma unroll
        for (int jj = 0; jj < 4; jj++) {
          int dx = qx0 + jj - px;
          if (dx >= -2 && dx <= 2) rr[jj] = t[qx0 + jj];
        }
      }
    }
  }
  vfloat4 v;
  v[0] = rr[0]; v[1] = rr[1]; v[2] = rr[2]; v[3] = rr[3];
  ((vfloat4*)out)[oidx] = v;
}

extern "C" void kernel_launch(void* const* d_in, const int* in_sizes, int n_in,
                              void* d_out, int out_size, void* d_ws, size_t ws_size,
                              hipStream_t stream) {
  const float* params = (const float*)d_in[0];  // (2, 35, 32, 32) fp32
  float* ws = (float*)d_ws;                     // ~1.6 MB used
  float* out = (float*)d_out;                   // (2, 5120, 5120) fp32

  dim3 g1(10, 16);
  tables_fused<<<g1, 256, 0, stream>>>(params, ws);

  dim3 g2(5, 5120, 2);
  fill_kernel<<<g2, 256, 0, stream>>>(ws, out);
}